// Round 11
// baseline (312.888 us; speedup 1.0000x reference)
//
#include <hip/hip_runtime.h>

// Causal MHA. B=4, S=2048, V=1024, H=16, hs=64. Output fp32.
// R11: attn2 = 128-row Q blocks, S^T-orientation softmax (2-shuffle
// reductions, b64 P stores), exp2-domain; qkv fp32 path vectorized.
#define B_  4
#define S_  2048
#define V_  1024
#define H_  16
#define HS_ 64
#define GK_ 1024
#define GN_ 1024

typedef unsigned short u16;
typedef __bf16 bf16x8 __attribute__((ext_vector_type(8)));
typedef float  f32x4  __attribute__((ext_vector_type(4)));

__device__ __forceinline__ float bf2f(u16 u) {
  return __uint_as_float(((unsigned int)u) << 16);
}
__device__ __forceinline__ float lo16(unsigned int w) { return __uint_as_float(w << 16); }
__device__ __forceinline__ float hi16(unsigned int w) { return __uint_as_float(w & 0xffff0000u); }
__device__ __forceinline__ u16 f2bf(float f) {
  unsigned int u = __float_as_uint(f);
  unsigned int r = u + 0x7fffu + ((u >> 16) & 1u);  // RNE
  return (u16)(r >> 16);
}
// native pack: 2 fp32 -> packed bf16 pair (v_cvt on gfx950)
__device__ __forceinline__ unsigned int pk2(float a, float b) {
  union { __bf16 h; u16 s; } ua, ub;
  ua.h = (__bf16)a; ub.h = (__bf16)b;
  return (unsigned int)ua.s | ((unsigned int)ub.s << 16);
}

// ---------------------------------------------------------------------------
// Input-storage detector (fp32 vs bf16; see R5/R7 notes).
// ---------------------------------------------------------------------------
__global__ __launch_bounds__(256) void detect_kernel(
    const unsigned int* __restrict__ x32, int* __restrict__ flag)
{
  __shared__ int zred[256];
  __shared__ int nred[256];
  const int tid = threadIdx.x;
  int nz = 0, nn = 0;
  for (int i = tid; i < 16384; i += 256) {
    unsigned int lo = x32[i] & 0xffffu;
    if (lo == 0u) nz++;
    if ((lo & 0x7f80u) == 0x7f80u && (lo & 0x7fu) != 0u) nn++;
  }
  zred[tid] = nz; nred[tid] = nn;
  __syncthreads();
  for (int s = 128; s > 0; s >>= 1) {
    if (tid < s) { zred[tid] += zred[tid + s]; nred[tid] += nred[tid + s]; }
    __syncthreads();
  }
  if (tid == 0) *flag = (zred[0] > 8192 || nred[0] > 0) ? 1 : 0;
}

// ---------------------------------------------------------------------------
// W_out -> bf16 (into q's dead workspace region).
// ---------------------------------------------------------------------------
__global__ __launch_bounds__(256) void wcvt_kernel(
    const void* __restrict__ w, u16* __restrict__ wb, const int* __restrict__ flag)
{
  const int i = (blockIdx.x * 256 + threadIdx.x) * 4;
  if (*flag) {
    float4 f = *(const float4*)((const float*)w + i);
    *(uint2*)(wb + i) = make_uint2(pk2(f.x, f.y), pk2(f.z, f.w));
  } else {
    *(uint2*)(wb + i) = *(const uint2*)((const u16*)w + i);
  }
}

// ---------------------------------------------------------------------------
// MFMA QKV projection (R10, fp32 loads now vectorized float4).
// ---------------------------------------------------------------------------
__global__ __launch_bounds__(256) void qkv_mfma_kernel(
    const void* __restrict__ x, const void* __restrict__ wqkv,
    u16* __restrict__ q, u16* __restrict__ k, u16* __restrict__ v,
    const int* __restrict__ flag)
{
  __shared__ __align__(16) u16 Ws[192 * 80];
  const int tid = threadIdx.x;
  const int isf32 = *flag;
  for (int idx = tid; idx < 192 * 4; idx += 256) {
    const int row = idx >> 2, c0 = (idx & 3) * 16;
    u16 t16[16];
    if (isf32) {
      const float4* gp = (const float4*)((const float*)wqkv + row * 64 + c0);
      float4 f0 = gp[0], f1 = gp[1], f2 = gp[2], f3 = gp[3];
      *(uint4*)t16       = make_uint4(pk2(f0.x,f0.y), pk2(f0.z,f0.w), pk2(f1.x,f1.y), pk2(f1.z,f1.w));
      *(uint4*)(t16 + 8) = make_uint4(pk2(f2.x,f2.y), pk2(f2.z,f2.w), pk2(f3.x,f3.y), pk2(f3.z,f3.w));
    } else {
      const u16* gp = (const u16*)wqkv + row * 64 + c0;
      *(uint4*)t16 = *(const uint4*)gp;
      *(uint4*)(t16 + 8) = *(const uint4*)(gp + 8);
    }
    *(uint4*)(Ws + row * 80 + c0) = *(uint4*)t16;
    *(uint4*)(Ws + row * 80 + c0 + 8) = *(uint4*)(t16 + 8);
  }
  __syncthreads();

  const int m0 = blockIdx.x * 128;
  const int w = tid >> 6, lane = tid & 63;
  const int ar = lane & 15, quad = lane >> 4;
  const int rbase = m0 + (w & 1) * 64;
  const int cbase = (w >> 1) * 96;

  bf16x8 af[4][2];
#pragma unroll
  for (int rt = 0; rt < 4; ++rt) {
    const size_t row = (size_t)(rbase + rt * 16 + ar) * 64;
    if (isf32) {
      const float* gp = (const float*)x + row;
#pragma unroll
      for (int ks = 0; ks < 2; ++ks) {
        const float4* g4 = (const float4*)(gp + ks * 32 + quad * 8);
        float4 f0 = g4[0], f1 = g4[1];
        uint4 upk = make_uint4(pk2(f0.x,f0.y), pk2(f0.z,f0.w), pk2(f1.x,f1.y), pk2(f1.z,f1.w));
        af[rt][ks] = *(bf16x8*)&upk;
      }
    } else {
      const u16* gp = (const u16*)x + row;
#pragma unroll
      for (int ks = 0; ks < 2; ++ks)
        af[rt][ks] = *(const bf16x8*)(gp + ks * 32 + quad * 8);
    }
  }

  f32x4 acc[4][6] = {};
#pragma unroll
  for (int ks = 0; ks < 2; ++ks)
#pragma unroll
    for (int t = 0; t < 6; ++t) {
      const bf16x8 bfr = *(const bf16x8*)(Ws + (cbase + t * 16 + ar) * 80 + ks * 32 + quad * 8);
#pragma unroll
      for (int rt = 0; rt < 4; ++rt)
        acc[rt][t] = __builtin_amdgcn_mfma_f32_16x16x32_bf16(af[rt][ks], bfr, acc[rt][t], 0, 0, 0);
    }

#pragma unroll
  for (int rt = 0; rt < 4; ++rt)
#pragma unroll
    for (int r = 0; r < 4; ++r) {
      const int m = rbase + rt * 16 + quad * 4 + r;
      const int z = m >> 15, s = (m >> 4) & (S_ - 1), h = m & (H_ - 1);
      const size_t base = (((size_t)z * H_ + h) * S_ + s) * HS_;
#pragma unroll
      for (int t = 0; t < 6; ++t) {
        const int e = cbase + t * 16 + ar;
        u16* dst = (e < 64) ? q : (e < 128) ? k : v;
        dst[base + (e & 63)] = f2bf(acc[rt][t][r]);
      }
    }
}

// ---------------------------------------------------------------------------
// R11 MFMA flash attention. Block = 4 waves, 128 Q rows (2 row-tiles/wave).
// S^T orientation: sacc = mfma(K-frag, Q-frag) -> lane holds S[i=lane&15]
// [j=jt*16+quad*4+r] => full score row in-lane; softmax reductions are 2
// shuffles (xor16/32); P stored as ds_write_b64; PV A-frag read stays b128.
// exp2 domain: Q pre-scaled by 0.125*log2(e). O acc rows = quad*4+r; alpha/l
// realigned via __shfl(_, quad*4+r).
// ---------------------------------------------------------------------------
__global__ __launch_bounds__(256) void attn2_kernel(
    const u16* __restrict__ q, const u16* __restrict__ k,
    const u16* __restrict__ v, u16* __restrict__ o)
{
  const int z = blockIdx.z, h = blockIdx.y;
  int qi = (blockIdx.x + 4 * z) & 15;
  if (h & 8) qi = 15 - qi;
  const int qb = qi * 128;
  const int tid = threadIdx.x;
  const int w = tid >> 6, lane = tid & 63;
  const int col = lane & 15, quad = lane >> 4;

  __shared__ __align__(16) u16 Ks[64 * 72];      // 9216 B
  __shared__ __align__(16) u16 Vt[64 * 72];      // 9216 B  (transposed [d][j])
  __shared__ __align__(16) u16 Ps[4][32 * 72];   // 18432 B (per-wave [i][j])

  const size_t hsb = ((size_t)z * H_ + h) * S_ * HS_;
  const int rowb0 = qb + w * 32;

  // Q B-fragments (n=i=lane&15), scaled by 0.125*log2(e)
  const float qsc = 0.125f * 1.44269504f;
  bf16x8 qf[2][2];
#pragma unroll
  for (int rt = 0; rt < 2; ++rt) {
    const u16* qp = q + hsb + (size_t)(rowb0 + rt * 16 + col) * HS_;
#pragma unroll
    for (int ks = 0; ks < 2; ++ks) {
      u16 t8[8];
      *(uint4*)t8 = *(const uint4*)(qp + ks * 32 + quad * 8);
      uint4 upk = make_uint4(pk2(bf2f(t8[0])*qsc, bf2f(t8[1])*qsc),
                             pk2(bf2f(t8[2])*qsc, bf2f(t8[3])*qsc),
                             pk2(bf2f(t8[4])*qsc, bf2f(t8[5])*qsc),
                             pk2(bf2f(t8[6])*qsc, bf2f(t8[7])*qsc));
      qf[rt][ks] = *(bf16x8*)&upk;
    }
  }

  const int sr = tid >> 2, sc = (tid & 3) * 16;    // K staging
  const int vrow = tid & 63, vc = (tid >> 6) * 16; // V staging (transpose)

  f32x4 oacc[2][4] = {};
  float m_run[2] = {-INFINITY, -INFINITY};
  float l_run[2] = {0.f, 0.f};

  for (int jb = 0; jb <= qb + 64; jb += 64) {
    const u16* kp = k + hsb + (size_t)(jb + sr) * HS_ + sc;
    uint4 k0 = *(const uint4*)kp;
    uint4 k1 = *(const uint4*)(kp + 8);
    const u16* vp = v + hsb + (size_t)(jb + vrow) * HS_ + vc;
    uint4 v0 = *(const uint4*)vp;
    uint4 v1 = *(const uint4*)(vp + 8);
    __syncthreads();
    *(uint4*)(Ks + sr * 72 + sc)     = k0;
    *(uint4*)(Ks + sr * 72 + sc + 8) = k1;
    {
      u16 t16[16];
      *(uint4*)t16 = v0; *(uint4*)(t16 + 8) = v1;
#pragma unroll
      for (int e = 0; e < 16; ++e) Vt[(vc + e) * 72 + vrow] = t16[e];
    }
    __syncthreads();

    // hoist V B-frags (shared across both row-tiles)
    bf16x8 vf[4][2];
#pragma unroll
    for (int nt = 0; nt < 4; ++nt)
#pragma unroll
      for (int ks = 0; ks < 2; ++ks)
        vf[nt][ks] = *(const bf16x8*)(Vt + (nt * 16 + col) * 72 + ks * 32 + quad * 8);

#pragma unroll
    for (int rt = 0; rt < 2; ++rt) {
      const int rowb = rowb0 + rt * 16;
      if (jb > rowb + 15) continue;      // tile entirely above the diagonal

      // S^T = K . Q^T : D[m=j][n=i]
      f32x4 sacc[4] = {};
#pragma unroll
      for (int ks = 0; ks < 2; ++ks)
#pragma unroll
        for (int jt = 0; jt < 4; ++jt) {
          const bf16x8 kf = *(const bf16x8*)(Ks + (jt * 16 + col) * 72 + ks * 32 + quad * 8);
          sacc[jt] = __builtin_amdgcn_mfma_f32_16x16x32_bf16(kf, qf[rt][ks], sacc[jt], 0, 0, 0);
        }
      // lane holds S[i = rowb+col][j = jb + jt*16 + quad*4 + r] (log2 domain)
      float s[4][4];
#pragma unroll
      for (int jt = 0; jt < 4; ++jt)
#pragma unroll
        for (int r = 0; r < 4; ++r) s[jt][r] = sacc[jt][r];

      if (jb + 64 > rowb) {              // diagonal region: mask j > i
        const int iglob = rowb + col;
#pragma unroll
        for (int jt = 0; jt < 4; ++jt)
#pragma unroll
          for (int r = 0; r < 4; ++r)
            if (jb + jt * 16 + quad * 4 + r > iglob) s[jt][r] = -INFINITY;
      }

      // row max (16 in-lane + xor16/32)
      float mr = s[0][0];
#pragma unroll
      for (int jt = 0; jt < 4; ++jt)
#pragma unroll
        for (int r = 0; r < 4; ++r) mr = fmaxf(mr, s[jt][r]);
      mr = fmaxf(mr, __shfl_xor(mr, 16));
      mr = fmaxf(mr, __shfl_xor(mr, 32));
      const float mn = fmaxf(m_run[rt], mr);
      const float alpha = exp2f(m_run[rt] - mn);
      m_run[rt] = mn;

      float p[4][4], ls = 0.f;
#pragma unroll
      for (int jt = 0; jt < 4; ++jt)
#pragma unroll
        for (int r = 0; r < 4; ++r) {
          p[jt][r] = exp2f(s[jt][r] - mn);
          ls += p[jt][r];
        }
      ls += __shfl_xor(ls, 16);
      ls += __shfl_xor(ls, 32);
      l_run[rt] = l_run[rt] * alpha + ls;

      // rescale O (rows quad*4+r): realign alpha from lane quad*4+r
      float ar_[4];
#pragma unroll
      for (int r = 0; r < 4; ++r) ar_[r] = __shfl(alpha, quad * 4 + r);
#pragma unroll
      for (int nt = 0; nt < 4; ++nt)
#pragma unroll
        for (int r = 0; r < 4; ++r) oacc[rt][nt][r] *= ar_[r];

      // P -> LDS, b64 stores ([i][j], stride 72)
      u16* pp = Ps[w] + (rt * 16 + col) * 72;
#pragma unroll
      for (int jt = 0; jt < 4; ++jt)
        *(uint2*)(pp + jt * 16 + quad * 4) =
            make_uint2(pk2(p[jt][0], p[jt][1]), pk2(p[jt][2], p[jt][3]));

      // PV: O[i][d] += P[i][j] V[j][d]
#pragma unroll
      for (int ks = 0; ks < 2; ++ks) {
        const bf16x8 pf = *(const bf16x8*)(Ps[w] + (rt * 16 + col) * 72 + ks * 32 + quad * 8);
#pragma unroll
        for (int nt = 0; nt < 4; ++nt)
          oacc[rt][nt] = __builtin_amdgcn_mfma_f32_16x16x32_bf16(pf, vf[nt][ks], oacc[rt][nt], 0, 0, 0);
      }
    }
  }

  // epilogue: o[i][h*64+d] = O/l ; l realigned from lane quad*4+r
  u16* ob = o + (size_t)z * S_ * V_ + h * HS_;
#pragma unroll
  for (int rt = 0; rt < 2; ++rt) {
    float linv[4];
#pragma unroll
    for (int r = 0; r < 4; ++r) linv[r] = 1.0f / __shfl(l_run[rt], quad * 4 + r);
    const int row0 = rowb0 + rt * 16 + quad * 4;
#pragma unroll
    for (int nt = 0; nt < 4; ++nt)
#pragma unroll
      for (int r = 0; r < 4; ++r)
        ob[(size_t)(row0 + r) * V_ + nt * 16 + col] = f2bf(oacc[rt][nt][r] * linv[r]);
  }
}

// ---------------------------------------------------------------------------
// Output projection, MFMA NT-GEMM (R9, unchanged).
// ---------------------------------------------------------------------------
__global__ __launch_bounds__(256) void oproj_mfma_kernel(
    const u16* __restrict__ a, const u16* __restrict__ bw, float* __restrict__ c)
{
  __shared__ __align__(16) u16 As[128 * 40];
  __shared__ __align__(16) u16 Bs[128 * 40];
  const int tid = threadIdx.x;
  const int m0 = blockIdx.x * 128;
  const int n0 = blockIdx.y * 128;
  const int w = tid >> 6, lane = tid & 63;
  const int col = lane & 15, quad = lane >> 4;
  const int qr = (w & 1) * 64;
  const int qc = (w >> 1) * 64;

  f32x4 acc[4][4] = {};

  const int sr = tid >> 2;
  const int sk = (tid & 3) * 8;
  const u16* ga = a  + (size_t)(m0 + sr) * GK_ + sk;
  const u16* gb = bw + (size_t)(n0 + sr) * GK_ + sk;

  for (int k0 = 0; k0 < GK_; k0 += 32) {
    uint4 a0 = *(const uint4*)(ga + k0);
    uint4 a1 = *(const uint4*)(ga + (size_t)64 * GK_ + k0);
    uint4 b0 = *(const uint4*)(gb + k0);
    uint4 b1 = *(const uint4*)(gb + (size_t)64 * GK_ + k0);
    __syncthreads();
    *(uint4*)(As + sr * 40 + sk)        = a0;
    *(uint4*)(As + (64 + sr) * 40 + sk) = a1;
    *(uint4*)(Bs + sr * 40 + sk)        = b0;
    *(uint4*)(Bs + (64 + sr) * 40 + sk) = b1;
    __syncthreads();

    bf16x8 af[4], bfr[4];
#pragma unroll
    for (int i = 0; i < 4; ++i) {
      af[i]  = *(const bf16x8*)(As + (qr + i * 16 + col) * 40 + quad * 8);
      bfr[i] = *(const bf16x8*)(Bs + (qc + i * 16 + col) * 40 + quad * 8);
    }
#pragma unroll
    for (int i = 0; i < 4; ++i)
#pragma unroll
      for (int j = 0; j < 4; ++j)
        acc[i][j] = __builtin_amdgcn_mfma_f32_16x16x32_bf16(af[i], bfr[j], acc[i][j], 0, 0, 0);
  }

#pragma unroll
  for (int i = 0; i < 4; ++i)
#pragma unroll
    for (int j = 0; j < 4; ++j)
#pragma unroll
      for (int r = 0; r < 4; ++r)
        c[(size_t)(m0 + qr + i * 16 + quad * 4 + r) * GN_ + n0 + qc + j * 16 + col]
            = acc[i][j][r];
}

// ---------------------------------------------------------------------------
// Fallback vector qkv/oproj (per-batch mode; not exercised when ws is full).
// ---------------------------------------------------------------------------
__global__ __launch_bounds__(256) void qkv_kernel(
    const void* __restrict__ x, int b0, const void* __restrict__ w,
    u16* __restrict__ q, u16* __restrict__ k, u16* __restrict__ v,
    const int* __restrict__ flag)
{
  __shared__ __align__(16) float Ws[192 * 64];
  const int tid = threadIdx.x;
  const int isf32 = *flag;
  if (isf32) {
    for (int i = tid; i < 192 * 64; i += 256) Ws[i] = ((const float*)w)[i];
  } else {
    for (int i = tid; i < 192 * 64; i += 256) Ws[i] = bf2f(((const u16*)w)[i]);
  }
  __syncthreads();

  const int th = blockIdx.x * 256 + tid;
  const int h = th & (H_ - 1);
  const int s = th >> 4;
  const int b = b0;
  const size_t xoff = ((size_t)b * S_ + s) * V_ + h * HS_;

  float xf[64];
  if (isf32) {
    const float4* xp = (const float4*)((const float*)x + xoff);
#pragma unroll
    for (int i = 0; i < 16; ++i) {
      float4 u = xp[i];
      xf[4*i+0] = u.x; xf[4*i+1] = u.y; xf[4*i+2] = u.z; xf[4*i+3] = u.w;
    }
  } else {
    const uint4* xp = (const uint4*)((const u16*)x + xoff);
#pragma unroll
    for (int i = 0; i < 8; ++i) {
      uint4 u = xp[i];
      xf[8*i+0] = lo16(u.x); xf[8*i+1] = hi16(u.x);
      xf[8*i+2] = lo16(u.y); xf[8*i+3] = hi16(u.y);
      xf[8*i+4] = lo16(u.z); xf[8*i+5] = hi16(u.z);
      xf[8*i+6] = lo16(u.w); xf[8*i+7] = hi16(u.w);
    }
  }

  const size_t obase = ((size_t)h * S_ + s) * HS_;
#pragma unroll 1
  for (int eg = 0; eg < 12; ++eg) {
    float acc[16];
#pragma unroll
    for (int ee = 0; ee < 16; ++ee) {
      const float4* wr = (const float4*)&Ws[(eg * 16 + ee) * 64];
      float a = 0.f;
#pragma unroll
      for (int d4 = 0; d4 < 16; ++d4) {
        float4 wv = wr[d4];
        a += xf[d4*4+0]*wv.x + xf[d4*4+1]*wv.y + xf[d4*4+2]*wv.z + xf[d4*4+3]*wv.w;
      }
      acc[ee] = a;
    }
    u16* dst = (eg < 4) ? q : (eg < 8) ? k : v;
    const int d0 = (eg & 3) * 16;
    unsigned int p[8];
#pragma unroll
    for (int t = 0; t < 8; ++t) p[t] = pk2(acc[2*t], acc[2*t+1]);
    uint4* dp = (uint4*)(dst + obase + d0);
    dp[0] = make_uint4(p[0], p[1], p[2], p[3]);
    dp[1] = make_uint4(p[4], p[5], p[6], p[7]);
  }
}

__global__ __launch_bounds__(256) void oproj_vec_kernel(
    const u16* __restrict__ o, const void* __restrict__ w,
    float* __restrict__ out, const int* __restrict__ flag)
{
  __shared__ __align__(16) float At[64 * 68];
  __shared__ __align__(16) float Wt[64 * 68];
  const int tid = threadIdx.x;
  const int m0 = blockIdx.x * 64;
  const int n0 = blockIdx.y * 64;
  const int tr = tid >> 4, tc = tid & 15;
  const int isf32 = *flag;
  const int srow = tid >> 2, sc = (tid & 3) * 16;

  float acc[4][4] = {};

  for (int k0 = 0; k0 < GK_; k0 += 64) {
    float av[16], wv[16];
    {
      const u16* gp = o + (size_t)(m0 + srow) * GK_ + k0 + sc;
      uint4 u0 = *(const uint4*)gp;
      uint4 u1 = *(const uint4*)(gp + 8);
      av[0]=lo16(u0.x); av[1]=hi16(u0.x); av[2]=lo16(u0.y); av[3]=hi16(u0.y);
      av[4]=lo16(u0.z); av[5]=hi16(u0.z); av[6]=lo16(u0.w); av[7]=hi16(u0.w);
      av[8]=lo16(u1.x); av[9]=hi16(u1.x); av[10]=lo16(u1.y); av[11]=hi16(u1.y);
      av[12]=lo16(u1.z); av[13]=hi16(u1.z); av[14]=lo16(u1.w); av[15]=hi16(u1.w);
    }
    if (isf32) {
      const float4* gp = (const float4*)((const float*)w + (size_t)(n0 + srow) * GK_ + k0 + sc);
#pragma unroll
      for (int i = 0; i < 4; ++i) {
        float4 f = gp[i];
        wv[4*i+0]=f.x; wv[4*i+1]=f.y; wv[4*i+2]=f.z; wv[4*i+3]=f.w;
      }
    } else {
      const u16* gp = (const u16*)w + (size_t)(n0 + srow) * GK_ + k0 + sc;
      uint4 u0 = *(const uint4*)gp;
      uint4 u1 = *(const uint4*)(gp + 8);
      wv[0]=lo16(u0.x); wv[1]=hi16(u0.x); wv[2]=lo16(u0.y); wv[3]=hi16(u0.y);
      wv[4]=lo16(u0.z); wv[5]=hi16(u0.z); wv[6]=lo16(u0.w); wv[7]=hi16(u0.w);
      wv[8]=lo16(u1.x); wv[9]=hi16(u1.x); wv[10]=lo16(u1.y); wv[11]=hi16(u1.y);
      wv[12]=lo16(u1.z); wv[13]=hi16(u1.z); wv[14]=lo16(u1.w); wv[15]=hi16(u1.w);
    }
    __syncthreads();
#pragma unroll
    for (int i = 0; i < 16; ++i) {
      At[(sc + i) * 68 + srow] = av[i];
      Wt[(sc + i) * 68 + srow] = wv[i];
    }
    __syncthreads();

#pragma unroll 4
    for (int kk = 0; kk < 64; ++kk) {
      float4 a4 = *(const float4*)&At[kk * 68 + tr * 4];
      float4 w4 = *(const float4*)&Wt[kk * 68 + tc * 4];
      acc[0][0] += a4.x*w4.x; acc[0][1] += a4.x*w4.y; acc[0][2] += a4.x*w4.z; acc[0][3] += a4.x*w4.w;
      acc[1][0] += a4.y*w4.x; acc[1][1] += a4.y*w4.y; acc[1][2] += a4.y*w4.z; acc[1][3] += a4.y*w4.w;
      acc[2][0] += a4.z*w4.x; acc[2][1] += a4.z*w4.y; acc[2][2] += a4.z*w4.z; acc[2][3] += a4.z*w4.w;
      acc[3][0] += a4.w*w4.x; acc[3][1] += a4.w*w4.y; acc[3][2] += a4.w*w4.z; acc[3][3] += a4.w*w4.w;
    }
  }

#pragma unroll
  for (int r = 0; r < 4; ++r) {
    const int row = m0 + tr * 4 + r;
    *(float4*)(out + (size_t)row * GN_ + n0 + tc * 4) =
        make_float4(acc[r][0], acc[r][1], acc[r][2], acc[r][3]);
  }
}

// ---------------------------------------------------------------------------
extern "C" void kernel_launch(void* const* d_in, const int* in_sizes, int n_in,
                              void* d_out, int out_size, void* d_ws, size_t ws_size,
                              hipStream_t stream) {
  const void* x = d_in[0];
  const void* wqkv = (n_in > 1) ? d_in[1] : d_in[0];
  const void* wout = (n_in > 2) ? d_in[2] : d_in[0];
  for (int i = 0; i < n_in; ++i) {
    if      (in_sizes[i] == B_ * S_ * V_)  x    = d_in[i];
    else if (in_sizes[i] == 3 * HS_ * HS_) wqkv = d_in[i];
    else if (in_sizes[i] == V_ * V_)       wout = d_in[i];
  }
  float* out = (float*)d_out;

  const size_t per_b = (size_t)H_ * S_ * HS_;
  const size_t SV = (size_t)S_ * V_;
  int* flag = (int*)d_ws;
  const bool full = ws_size >= (16 + 16 * per_b * sizeof(u16));
  const size_t stride = full ? 4 * per_b : per_b;
  u16* q = (u16*)((char*)d_ws + 16);
  u16* k = q + stride;
  u16* v = k + stride;
  u16* o = v + stride;

  detect_kernel<<<dim3(1), dim3(256), 0, stream>>>((const unsigned int*)x, flag);
  if (full) {
    qkv_mfma_kernel<<<dim3((B_ * S_ * H_) / 128), dim3(256), 0, stream>>>(
        x, wqkv, q, k, v, flag);
    attn2_kernel<<<dim3(16, 16, B_), dim3(256), 0, stream>>>(q, k, v, o);
    u16* wb = q;   // q dead after attn
    wcvt_kernel<<<dim3((V_ * V_) / 1024), dim3(256), 0, stream>>>(wout, wb, flag);
    oproj_mfma_kernel<<<dim3((B_ * S_) / 128, GN_ / 128), dim3(256), 0, stream>>>(o, wb, out);
  } else {
    for (int b = 0; b < B_; ++b) {
      qkv_kernel<<<dim3(128, 1, 1), dim3(256), 0, stream>>>(x, b, wqkv, q, k, v, flag);
      attn2_kernel<<<dim3(16, 16, 1), dim3(256), 0, stream>>>(q, k, v, o);
      oproj_vec_kernel<<<dim3(32, 16, 1), dim3(256), 0, stream>>>(o, wout, out + (size_t)b * SV, flag);
    }
  }
}